// Round 1
// baseline (232.871 us; speedup 1.0000x reference)
//
#include <hip/hip_runtime.h>
#include <hip/hip_bf16.h>

#define T_STEPS 512
#define BATCH 32
#define NST 64
#define DIM 1024

typedef _Float16 f16x8 __attribute__((ext_vector_type(8)));
typedef _Float16 f16x4 __attribute__((ext_vector_type(4)));
typedef _Float16 f16x2 __attribute__((ext_vector_type(2)));
typedef float f32x4 __attribute__((ext_vector_type(4)));

__device__ __forceinline__ void gl_lds16(const void* g, void* l) {
  __builtin_amdgcn_global_load_lds(
      (const __attribute__((address_space(1))) void*)g,
      (__attribute__((address_space(3))) void*)l, 16, 0, 0);
}

// ---------------- W concat + fp16 convert ----------------
// Wc[256][1024] fp16, row order [Wk | Wq | Wv | Wa].
__global__ __launch_bounds__(256) void wconv(
    const float* __restrict__ Wk, const float* __restrict__ Wv,
    const float* __restrict__ Wq, const float* __restrict__ Wa,
    _Float16* __restrict__ Wc) {
  const int n = blockIdx.x;
  const int g = n >> 6, r = n & 63;
  const float* W = (g == 0) ? Wk : (g == 1) ? Wq : (g == 2) ? Wv : Wa;
  float4 v = *(const float4*)(W + (size_t)r * DIM + threadIdx.x * 4);
  f16x4 h = {(_Float16)v.x, (_Float16)v.y, (_Float16)v.z, (_Float16)v.w};
  *(f16x4*)(Wc + (size_t)n * DIM + threadIdx.x * 4) = h;
}

// ---------------- Projection GEMM (m97-style) ----------------
// projh[m][256] fp16, cols [k(64) | q(64) | v,ax interleaved(128)].
__global__ __launch_bounds__(256) void proj_gemm(
    const float* __restrict__ x, const _Float16* __restrict__ Wc,
    _Float16* __restrict__ projh) {
  const int m0 = blockIdx.x * 64;
  const int n0 = blockIdx.y * 128;
  const int tid = threadIdx.x;
  const int lane = tid & 63, wv = tid >> 6;
  const int wm = wv >> 1, wn = wv & 1;
  const int fm = lane & 15, fq = lane >> 4;

  __shared__ __align__(16) _Float16 Al[64 * 40];
  __shared__ __align__(16) _Float16 Bl[2][128 * 32];

  const int bro = wv * 32 + (lane >> 2);
  const int bchunk = (lane & 3) ^ ((lane >> 3) & 3);
  const _Float16* gB = Wc + (size_t)(n0 + bro) * DIM + bchunk * 8;
  const int bl_off = bro * 32 + (lane & 3) * 8;

  const int arow = tid >> 2;
  const int acol = (tid & 3) * 8;
  const float* gA = x + (size_t)(m0 + arow) * DIM + acol;

  f32x4 acc[2][4];
#pragma unroll
  for (int mi = 0; mi < 2; ++mi)
#pragma unroll
    for (int ni = 0; ni < 4; ++ni) acc[mi][ni] = (f32x4){0.f, 0.f, 0.f, 0.f};

#define STAGE_B(buf, k0)                                       \
  {                                                            \
    _Pragma("unroll") for (int j = 0; j < 2; ++j)              \
        gl_lds16(gB + (size_t)j * 16 * DIM + (k0),             \
                 &Bl[buf][bl_off + j * 16 * 32]);              \
  }
  float4 xa, xb;
#define LOAD_A(k0)                          \
  {                                         \
    xa = *(const float4*)(gA + (k0));       \
    xb = *(const float4*)(gA + (k0) + 4);   \
  }

  STAGE_B(0, 0);
  LOAD_A(0);
  const int aswz = (fq ^ ((fm >> 1) & 3)) * 8;
  for (int kt = 0; kt < 32; ++kt) {
    __syncthreads();
    f16x8 ah;
    ah[0] = (_Float16)xa.x; ah[1] = (_Float16)xa.y;
    ah[2] = (_Float16)xa.z; ah[3] = (_Float16)xa.w;
    ah[4] = (_Float16)xb.x; ah[5] = (_Float16)xb.y;
    ah[6] = (_Float16)xb.z; ah[7] = (_Float16)xb.w;
    *(f16x8*)&Al[arow * 40 + acol] = ah;
    __syncthreads();
    if (kt + 1 < 32) {
      LOAD_A(kt * 32 + 32);
      STAGE_B((kt + 1) & 1, kt * 32 + 32);
    }
    f16x8 afr[2], bfr[4];
#pragma unroll
    for (int mi = 0; mi < 2; ++mi)
      afr[mi] = *(const f16x8*)&Al[(wm * 32 + mi * 16 + fm) * 40 + fq * 8];
#pragma unroll
    for (int ni = 0; ni < 4; ++ni) {
      const int row = wn * 64 + ni * 16 + fm;
      bfr[ni] = *(const f16x8*)&Bl[kt & 1][row * 32 + aswz];
    }
#pragma unroll
    for (int mi = 0; mi < 2; ++mi)
#pragma unroll
      for (int ni = 0; ni < 4; ++ni)
        acc[mi][ni] =
            __builtin_amdgcn_mfma_f32_16x16x32_f16(afr[mi], bfr[ni], acc[mi][ni], 0, 0, 0);
  }
#undef STAGE_B
#undef LOAD_A

#pragma unroll
  for (int mi = 0; mi < 2; ++mi)
#pragma unroll
    for (int ni = 0; ni < 4; ++ni) {
      const int gcol = n0 + wn * 64 + ni * 16 + fm;
      const int pcol = gcol < 128 ? gcol
                     : (gcol < 192 ? 128 + 2 * (gcol - 128) : 129 + 2 * (gcol - 192));
#pragma unroll
      for (int r = 0; r < 4; ++r) {
        const int grow = m0 + wm * 32 + mi * 16 + fq * 4 + r;
        projh[(size_t)grow * 256 + pcol] = (_Float16)acc[mi][ni][r];
      }
    }
}

// ---------------- Gram kernel: g[b][t] = k_{t-1} . k_t ----------------
// Pure-input scalar used by the scan's lookahead reformulation. g[b][0] = 0.
__global__ __launch_bounds__(256) void gram_kernel(
    const _Float16* __restrict__ projh, float* __restrict__ gmat) {
  const int b = blockIdx.x >> 1;
  const int t = (blockIdx.x & 1) * 256 + threadIdx.x;
  float acc = 0.f;
  if (t > 0) {
    const _Float16* ka = projh + ((size_t)(t - 1) * BATCH + b) * 256;
    const _Float16* kb = projh + ((size_t)t * BATCH + b) * 256;
#pragma unroll
    for (int j = 0; j < 64; j += 8) {
      f16x8 va = *(const f16x8*)(ka + j);
      f16x8 vb = *(const f16x8*)(kb + j);
#pragma unroll
      for (int e = 0; e < 8; ++e) acc = fmaf((float)va[e], (float)vb[e], acc);
    }
  }
  gmat[(size_t)b * T_STEPS + t] = acc;
}

// ---------------- Sequential scan ----------------
// 128 blocks = (b, 16-row group), 256 threads = 16 rows x 16 lanes.
// Latency-bound recurrence; chain shortened via 1-step lookahead:
//   retrieved_t = al_{t-1} * fma(e_{t-1}, v_{t-1}*g_t, u_t)
//   u_t = S_{t-2}.k_t  (computed one step early, off-chain)
//   g_t = k_{t-1}.k_t  (precomputed Gram scalar)
// Critical loop per step: mul, fma, med3, exp2, add, rcp, mul ≈ 7 dep ops.
__device__ __forceinline__ float red16(float x) {
  int v = __builtin_amdgcn_update_dpp(0, __float_as_int(x), 0xB1, 0xF, 0xF, true);
  x += __int_as_float(v);
  v = __builtin_amdgcn_update_dpp(0, __float_as_int(x), 0x4E, 0xF, 0xF, true);
  x += __int_as_float(v);
  v = __builtin_amdgcn_update_dpp(0, __float_as_int(x), 0x124, 0xF, 0xF, true);
  x += __int_as_float(v);
  v = __builtin_amdgcn_update_dpp(0, __float_as_int(x), 0x128, 0xF, 0xF, true);
  x += __int_as_float(v);
  return x;
}

__global__ __launch_bounds__(256) void scan_kernel(
    const _Float16* __restrict__ projh, const float* __restrict__ gmat,
    const float* __restrict__ S0,
    const float* __restrict__ d_alpha, const float* __restrict__ b_alpha,
    float* __restrict__ out, float* __restrict__ Sout) {
  const int b = blockIdx.x >> 2;
  const int rg = blockIdx.x & 3;
  const int tid = threadIdx.x;
  const int c = tid & 15;          // column lane
  const int r = rg * 16 + (tid >> 4);
  const int j0 = c * 4;

  __shared__ __align__(16) _Float16 lbuf[2 * 2048];  // 2 chunks x 8 steps x 256
  __shared__ __align__(8) float glds[T_STEPS];       // Gram scalars for this b

  float s[4];
  {
    float4 v = *(const float4*)(S0 + ((size_t)b * NST + r) * NST + j0);
    s[0] = v.x; s[1] = v.y; s[2] = v.z; s[3] = v.w;
  }
  constexpr float NL2E = -1.44269504088896340736f;  // -log2(e)
  const float da2 = d_alpha[r] * NL2E;
  const float ba2 = b_alpha[r] * NL2E;

  const _Float16* gp = projh + (size_t)b * 256;
  const int lidx = (tid >> 5) * 256 + (tid & 31) * 8;
#define GADDR(ch) (gp + (size_t)((ch) * 8 + (tid >> 5)) * (BATCH * 256) + (tid & 31) * 8)

  {  // stage all 512 Gram scalars once
    float2 g2 = *(const float2*)(gmat + (size_t)b * T_STEPS + tid * 2);
    *(float2*)(glds + tid * 2) = g2;
  }
  float4 rA;
  rA = *(const float4*)GADDR(0); *(float4*)(lbuf + lidx) = rA;
  rA = *(const float4*)GADDR(1); *(float4*)(lbuf + 2048 + lidx) = rA;
  rA = *(const float4*)GADDR(2);
  __syncthreads();

  // distance-2 register prefetch (4 slots), so k_{t+1} ds_reads never stall
  f16x4 kf[4], qf[4];
  f16x2 vaf[4];
  float gv[4];
#define PREF(tn)                                                             \
  {                                                                          \
    const int pp = (tn) & 3;                                                 \
    const _Float16* Pn = lbuf + (((tn) >> 3) & 1) * 2048 + ((tn) & 7) * 256; \
    kf[pp] = *(const f16x4*)(Pn + j0);                                       \
    qf[pp] = *(const f16x4*)(Pn + 64 + j0);                                  \
    vaf[pp] = *(const f16x2*)(Pn + 128 + 2 * r);                             \
    gv[pp] = glds[(tn)];                                                     \
  }

  PREF(0);
  PREF(1);
  qf[3] = qf[0];  // t=0 reads qf[(t-1)&3]=qf[3]; result discarded but must be finite

  // prologue state: al_{-1}=1, e_{-1}=0 (cc_{-1}=0), S_{-2}=S_{-1}=S_init
  float kc[4];  // k_t floats entering step t (here k_0)
  kc[0] = (float)kf[0][0]; kc[1] = (float)kf[0][1];
  kc[2] = (float)kf[0][2]; kc[3] = (float)kf[0][3];
  float u;
  {
    const float pa = fmaf(s[1], kc[1], s[0] * kc[0]);
    const float pb = fmaf(s[3], kc[3], s[2] * kc[2]);
    u = red16(pa + pb);  // u_0 = S_init . k_0
  }
  float al = 1.f, e = 0.f, vp = 0.f;
  float cck[4] = {0.f, 0.f, 0.f, 0.f};  // cc_{t-1} * k_{t-1}

  for (int ch = 0; ch < 64; ++ch) {
#pragma unroll
    for (int si = 0; si < 8; ++si) {
      const int t = ch * 8 + si;
      const int p = si & 3;          // == t & 3       (ch*8 ≡ 0 mod 4)
      const int pn1 = (si + 1) & 3;  // == (t+1) & 3
      const int pm1 = (si + 3) & 3;  // == (t-1) & 3
      if (t + 2 < T_STEPS) PREF(t + 2);

      // ---- critical chain: al_{t-1} -> al_t (7 dep ops) ----
      const float axv = (float)vaf[p][1];
      const float vt = (float)vaf[p][0];
      const float w = fmaf(e, vp * gv[p], u);  // u_t + e*v*g (vp*gv off-chain)
      const float rr = al * w;                 // retrieved_t
      float z2 = fmaf(da2, rr, fmaf(axv, NL2E, ba2));  // -log2e*(ax+da*rr+ba)
      z2 = fminf(fmaxf(z2, -43.3f), 43.3f);            // med3, == clamp z to ±30
      const float eN = __builtin_amdgcn_exp2f(z2);     // exp(-z)
      const float alN = __builtin_amdgcn_rcpf(1.f + eN);  // sigmoid(z)
      const float ccN = (eN * vt) * alN;                  // (1-alpha)*v

      // ---- S_{t-1} = al_{t-1}*S_{t-2} + cc_{t-1}*k_{t-1} (product carried) ----
      s[0] = fmaf(al, s[0], cck[0]);
      s[1] = fmaf(al, s[1], cck[1]);
      s[2] = fmaf(al, s[2], cck[2]);
      s[3] = fmaf(al, s[3], cck[3]);

      // ---- u_{t+1} = S_{t-1} . k_{t+1} (one step of slack before use) ----
      float kn[4];
      kn[0] = (float)kf[pn1][0]; kn[1] = (float)kf[pn1][1];
      kn[2] = (float)kf[pn1][2]; kn[3] = (float)kf[pn1][3];
      const float ua = fmaf(s[1], kn[1], s[0] * kn[0]);
      const float ub = fmaf(s[3], kn[3], s[2] * kn[2]);
      const float uN = red16(ua + ub);

      // ---- h_{t-1} = S_{t-1} . q_{t-1}; self-gated output (fully off-chain) ----
      const float q0 = (float)qf[pm1][0], q1 = (float)qf[pm1][1];
      const float q2 = (float)qf[pm1][2], q3 = (float)qf[pm1][3];
      const float ha = fmaf(s[1], q1, s[0] * q0);
      const float hb = fmaf(s[3], q3, s[2] * q2);
      const float h = red16(ha + hb);
      if (c == 0 && t > 0) {
        const float sg =
            __builtin_amdgcn_rcpf(1.f + __builtin_amdgcn_exp2f(h * NL2E));
        out[((size_t)(t - 1) * BATCH + b) * NST + r] = (h * h) * sg;
      }

      // ---- rotate carried state ----
      cck[0] = ccN * kc[0]; cck[1] = ccN * kc[1];
      cck[2] = ccN * kc[2]; cck[3] = ccN * kc[3];
      kc[0] = kn[0]; kc[1] = kn[1]; kc[2] = kn[2]; kc[3] = kn[3];
      al = alN; e = eN; vp = vt; u = uN;
    }
    if (ch + 2 < 64) {
      __syncthreads();                                 // reads of buf[ch&1] done
      *(float4*)(lbuf + (ch & 1) * 2048 + lidx) = rA;  // stage chunk ch+2
      if (ch + 3 < 64) rA = *(const float4*)GADDR(ch + 3);
      __syncthreads();                                 // visible before read
    }
  }
#undef PREF
#undef GADDR

  // epilogue: S_511 = al_511*S_510 + cc_511*k_511 ; h_511 ; final stores
  s[0] = fmaf(al, s[0], cck[0]);
  s[1] = fmaf(al, s[1], cck[1]);
  s[2] = fmaf(al, s[2], cck[2]);
  s[3] = fmaf(al, s[3], cck[3]);
  {
    const float q0 = (float)qf[3][0], q1 = (float)qf[3][1];  // q_511 (511&3==3)
    const float q2 = (float)qf[3][2], q3 = (float)qf[3][3];
    const float ha = fmaf(s[1], q1, s[0] * q0);
    const float hb = fmaf(s[3], q3, s[2] * q2);
    const float h = red16(ha + hb);
    if (c == 0) {
      const float sg =
          __builtin_amdgcn_rcpf(1.f + __builtin_amdgcn_exp2f(h * NL2E));
      out[((size_t)(T_STEPS - 1) * BATCH + b) * NST + r] = (h * h) * sg;
    }
  }
  float4 o = {s[0], s[1], s[2], s[3]};
  *(float4*)(Sout + ((size_t)b * NST + r) * NST + j0) = o;
}

extern "C" void kernel_launch(void* const* d_in, const int* in_sizes, int n_in,
                              void* d_out, int out_size, void* d_ws, size_t ws_size,
                              hipStream_t stream) {
  const float* x  = (const float*)d_in[0];
  const float* S0 = (const float*)d_in[1];
  const float* Wk = (const float*)d_in[2];
  const float* Wv = (const float*)d_in[3];
  const float* Wq = (const float*)d_in[4];
  const float* Wa = (const float*)d_in[5];
  const float* da = (const float*)d_in[6];
  const float* ba = (const float*)d_in[7];

  float* out  = (float*)d_out;                        // [T,B,64]
  float* Sout = out + (size_t)T_STEPS * BATCH * NST;  // [B,64,64]
  _Float16* projh = (_Float16*)d_ws;                  // [16384][256] fp16 = 8 MB
  _Float16* Wc = (_Float16*)((char*)d_ws + (size_t)16384 * 256 * 2);       // 512 KB
  float* gmat = (float*)((char*)d_ws + (size_t)16384 * 256 * 2 + 512 * 1024);  // 64 KB

  wconv<<<256, 256, 0, stream>>>(Wk, Wv, Wq, Wa, Wc);
  dim3 ggrid(16384 / 64, 2);
  proj_gemm<<<ggrid, 256, 0, stream>>>(x, Wc, projh);
  gram_kernel<<<64, 256, 0, stream>>>(projh, gmat);
  scan_kernel<<<4 * BATCH, 256, 0, stream>>>(projh, gmat, S0, da, ba, out, Sout);
}

// Round 2
// 224.931 us; speedup vs baseline: 1.0353x; 1.0353x over previous
//
#include <hip/hip_runtime.h>
#include <hip/hip_bf16.h>

#define T_STEPS 512
#define BATCH 32
#define NST 64
#define DIM 1024

typedef _Float16 f16x8 __attribute__((ext_vector_type(8)));
typedef _Float16 f16x4 __attribute__((ext_vector_type(4)));
typedef _Float16 f16x2 __attribute__((ext_vector_type(2)));
typedef float f32x4 __attribute__((ext_vector_type(4)));

__device__ __forceinline__ void gl_lds16(const void* g, void* l) {
  __builtin_amdgcn_global_load_lds(
      (const __attribute__((address_space(1))) void*)g,
      (__attribute__((address_space(3))) void*)l, 16, 0, 0);
}

// ---------------- W concat + fp16 convert ----------------
// Wc[256][1024] fp16, row order [Wk | Wq | Wv | Wa].
__global__ __launch_bounds__(256) void wconv(
    const float* __restrict__ Wk, const float* __restrict__ Wv,
    const float* __restrict__ Wq, const float* __restrict__ Wa,
    _Float16* __restrict__ Wc) {
  const int n = blockIdx.x;
  const int g = n >> 6, r = n & 63;
  const float* W = (g == 0) ? Wk : (g == 1) ? Wq : (g == 2) ? Wv : Wa;
  float4 v = *(const float4*)(W + (size_t)r * DIM + threadIdx.x * 4);
  f16x4 h = {(_Float16)v.x, (_Float16)v.y, (_Float16)v.z, (_Float16)v.w};
  *(f16x4*)(Wc + (size_t)n * DIM + threadIdx.x * 4) = h;
}

// ---------------- Projection GEMM v2 ----------------
// BM=64, BN=256 (full width -> x read ONCE), BK=32.
// 256 blocks (1/CU), 512 threads = 8 waves (2/SIMD), wave grid 2m x 4n,
// wave tile 32m x 64n. A and B double-buffered in LDS, ONE barrier/K-step.
// B staged via global_load_lds (src pre-swizzled: chunk ^ ((row>>1)&3));
// A staged global->reg (1 iter of slack) -> cvt fp16 -> swizzled ds_write.
// projh[m][256] fp16, cols [k(64) | q(64) | v,ax interleaved(128)].
__global__ __launch_bounds__(512) void proj_gemm(
    const float* __restrict__ x, const _Float16* __restrict__ Wc,
    _Float16* __restrict__ projh) {
  const int m0 = blockIdx.x * 64;
  const int tid = threadIdx.x;
  const int lane = tid & 63, wv = tid >> 6;
  const int wm = wv >> 2, wn = wv & 3;
  const int fm = lane & 15, fq = lane >> 4;

  __shared__ __align__(16) _Float16 Bl[2][256 * 32];  // 2 x 16 KB
  __shared__ __align__(16) _Float16 Al[2][64 * 32];   // 2 x 4 KB

  // ---- B staging: 2 x gl_lds16 per thread per K-step ----
  // linear LDS pos p = i*8192B + tid*16B -> row = i*128 + (tid>>2), chunk = tid&3
  // source chunk = (tid&3) ^ ((tid>>3)&3)  (== chunk ^ ((row>>1)&3))
  const int brow = tid >> 2;
  const int bcg = (tid & 3) ^ ((tid >> 3) & 3);
  const _Float16* gB = Wc + (size_t)brow * DIM + bcg * 8;
  const int bdst = tid * 8;  // halves; == uniform + lane*8

#define STAGE_B(buf, k0)                                          \
  {                                                               \
    _Pragma("unroll") for (int i = 0; i < 2; ++i)                 \
        gl_lds16(gB + (size_t)i * 128 * DIM + (k0),               \
                 &Bl[buf][i * 4096 + bdst]);                      \
  }

  // ---- A staging: 1 float4 per thread per K-step ----
  const int arow = tid >> 3;             // 0..63
  const int afc = (tid & 7) * 4;         // float col within BK
  const float* gA = x + (size_t)(m0 + arow) * DIM + afc;
  // write b64 at chunk (tid>>1)&3 swizzled, half-offset (tid&1)*4
  const int awp = arow * 32 + ((((tid >> 1) & 3) ^ ((arow >> 1) & 3)) * 8) +
                  (tid & 1) * 4;

#define LOADX(rr, k0)                          \
  {                                            \
    rr = *(const float4*)(gA + (k0));          \
  }
#define CVT_WRITE_A(buf, rr)                                        \
  {                                                                 \
    f16x4 h = {(_Float16)rr.x, (_Float16)rr.y, (_Float16)rr.z,      \
               (_Float16)rr.w};                                     \
    *(f16x4*)&Al[buf][awp] = h;                                     \
  }

  f32x4 acc[2][4];
#pragma unroll
  for (int mi = 0; mi < 2; ++mi)
#pragma unroll
    for (int ni = 0; ni < 4; ++ni) acc[mi][ni] = (f32x4){0.f, 0.f, 0.f, 0.f};

  const int aswz = (fq ^ ((fm >> 1) & 3)) * 8;
  const int abase = (wm * 32 + fm) * 32 + aswz;
  const int bbase = (wn * 64 + fm) * 32 + aswz;

#define COMPUTE(cb)                                                     \
  {                                                                     \
    f16x8 afr[2], bfr[4];                                               \
    _Pragma("unroll") for (int mi = 0; mi < 2; ++mi)                    \
        afr[mi] = *(const f16x8*)&Al[cb][abase + mi * 16 * 32];         \
    _Pragma("unroll") for (int ni = 0; ni < 4; ++ni)                    \
        bfr[ni] = *(const f16x8*)&Bl[cb][bbase + ni * 16 * 32];         \
    _Pragma("unroll") for (int mi = 0; mi < 2; ++mi)                    \
        _Pragma("unroll") for (int ni = 0; ni < 4; ++ni)                \
            acc[mi][ni] = __builtin_amdgcn_mfma_f32_16x16x32_f16(       \
                afr[mi], bfr[ni], acc[mi][ni], 0, 0, 0);                \
  }

  float4 rE, rO;
  LOADX(rE, 0);
  STAGE_B(0, 0);
  LOADX(rO, 32);
  CVT_WRITE_A(0, rE);
  __syncthreads();

  for (int k2 = 0; k2 < 16; ++k2) {
    // even K-step kt = 2*k2 : compute buf0, stage buf1
    STAGE_B(1, (2 * k2 + 1) * 32);
    if (k2 < 15) LOADX(rE, (2 * k2 + 2) * 32);
    CVT_WRITE_A(1, rO);
    COMPUTE(0);
    __syncthreads();
    // odd K-step kt = 2*k2+1 : compute buf1, stage buf0
    if (k2 < 15) {
      STAGE_B(0, (2 * k2 + 2) * 32);
      LOADX(rO, (2 * k2 + 3) * 32);
      CVT_WRITE_A(0, rE);
    }
    COMPUTE(1);
    __syncthreads();
  }
#undef STAGE_B
#undef LOADX
#undef CVT_WRITE_A
#undef COMPUTE

  // C/D: col = lane&15, row = (lane>>4)*4 + reg. Remap cols: v,ax interleaved.
#pragma unroll
  for (int mi = 0; mi < 2; ++mi)
#pragma unroll
    for (int ni = 0; ni < 4; ++ni) {
      const int gcol = wn * 64 + ni * 16 + fm;
      const int pcol = gcol < 128 ? gcol
                     : (gcol < 192 ? 128 + 2 * (gcol - 128) : 129 + 2 * (gcol - 192));
#pragma unroll
      for (int r = 0; r < 4; ++r) {
        const int grow = m0 + wm * 32 + mi * 16 + fq * 4 + r;
        projh[(size_t)grow * 256 + pcol] = (_Float16)acc[mi][ni][r];
      }
    }
}

// ---------------- Sequential scan ----------------
// 128 blocks = (b, 16-row group), 256 threads = 16 rows x 16 lanes.
// Thread (r, c) owns S[b][r][4c..4c+3] in registers. 16-lane all-reduce via
// DPP: quad_perm xor1, xor2, row_ror:4, row_ror:8 (no DS pipe).
// proj staged through 2-chunk LDS ring (8 steps/chunk), loads 1 chunk ahead.
__device__ __forceinline__ float red16(float x) {
  int v = __builtin_amdgcn_update_dpp(0, __float_as_int(x), 0xB1, 0xF, 0xF, true);
  x += __int_as_float(v);
  v = __builtin_amdgcn_update_dpp(0, __float_as_int(x), 0x4E, 0xF, 0xF, true);
  x += __int_as_float(v);
  v = __builtin_amdgcn_update_dpp(0, __float_as_int(x), 0x124, 0xF, 0xF, true);
  x += __int_as_float(v);
  v = __builtin_amdgcn_update_dpp(0, __float_as_int(x), 0x128, 0xF, 0xF, true);
  x += __int_as_float(v);
  return x;
}

__global__ __launch_bounds__(256) void scan_kernel(
    const _Float16* __restrict__ projh, const float* __restrict__ S0,
    const float* __restrict__ d_alpha, const float* __restrict__ b_alpha,
    float* __restrict__ out, float* __restrict__ Sout) {
  const int b = blockIdx.x >> 2;
  const int rg = blockIdx.x & 3;
  const int tid = threadIdx.x;
  const int c = tid & 15;          // column lane
  const int r = rg * 16 + (tid >> 4);
  const int j0 = c * 4;

  __shared__ __align__(16) _Float16 lbuf[2 * 2048];  // 2 chunks x 8 steps x 256

  float s[4];
  {
    float4 v = *(const float4*)(S0 + ((size_t)b * NST + r) * NST + j0);
    s[0] = v.x; s[1] = v.y; s[2] = v.z; s[3] = v.w;
  }
  const float da = d_alpha[r];
  const float ba = b_alpha[r];

  const _Float16* gp = projh + (size_t)b * 256;
  const int lidx = (tid >> 5) * 256 + (tid & 31) * 8;
#define GADDR(ch) (gp + (size_t)((ch) * 8 + (tid >> 5)) * (BATCH * 256) + (tid & 31) * 8)

  float4 rA;
  rA = *(const float4*)GADDR(0); *(float4*)(lbuf + lidx) = rA;
  rA = *(const float4*)GADDR(1); *(float4*)(lbuf + 2048 + lidx) = rA;
  rA = *(const float4*)GADDR(2);
  __syncthreads();

  f16x4 kf[2], qf[2];
  f16x2 vaf[2];
#define PREF(tn)                                                           \
  {                                                                        \
    const int pp = (tn)&1;                                                 \
    const _Float16* Pn = lbuf + (((tn) >> 3) & 1) * 2048 + ((tn)&7) * 256; \
    kf[pp] = *(const f16x4*)(Pn + j0);                                     \
    qf[pp] = *(const f16x4*)(Pn + 64 + j0);                                \
    vaf[pp] = *(const f16x2*)(Pn + 128 + 2 * r);                           \
  }

  PREF(0);
  for (int ch = 0; ch < 64; ++ch) {
#pragma unroll
    for (int si = 0; si < 8; ++si) {
      const int t = ch * 8 + si;
      const int p = t & 1;
      if (t + 1 < T_STEPS) PREF(t + 1);

      const float k0 = (float)kf[p][0], k1 = (float)kf[p][1];
      const float k2 = (float)kf[p][2], k3 = (float)kf[p][3];
      const float q0 = (float)qf[p][0], q1 = (float)qf[p][1];
      const float q2 = (float)qf[p][2], q3 = (float)qf[p][3];
      const float vi = (float)vaf[p][0];
      const float axv = (float)vaf[p][1];

      // retrieved = S[r,:] . k (4 owned + 16-lane allreduce)
      const float pa = fmaf(s[0], k0, s[1] * k1);
      const float pb = fmaf(s[2], k2, s[3] * k3);
      const float rr = red16(pa + pb);

      float z = fmaf(da, rr, axv + ba);
      z = fminf(fmaxf(z, -30.f), 30.f);  // inf-safe (numerically exact in range)
      const float e = __expf(-z);
      const float al = __builtin_amdgcn_rcpf(1.f + e);  // sigmoid(z)
      const float cc = (e * vi) * al;                   // (1-al)*v

      // S = al*S + cc*k ; h = S_new . q
      s[0] = fmaf(al, s[0], cc * k0);
      s[1] = fmaf(al, s[1], cc * k1);
      s[2] = fmaf(al, s[2], cc * k2);
      s[3] = fmaf(al, s[3], cc * k3);
      const float ha = fmaf(s[0], q0, s[1] * q1);
      const float hb = fmaf(s[2], q2, s[3] * q3);
      const float h = red16(ha + hb);

      if (c == 0) {
        const float sg = __builtin_amdgcn_rcpf(1.f + __expf(-h));
        out[((size_t)t * BATCH + b) * NST + r] = h * h * sg;
      }
    }
    if (ch + 2 < 64) {
      __syncthreads();                                 // reads of buf[ch&1] done
      *(float4*)(lbuf + (ch & 1) * 2048 + lidx) = rA;  // stage chunk ch+2
      if (ch + 3 < 64) rA = *(const float4*)GADDR(ch + 3);
      __syncthreads();                                 // visible before read
    }
  }
#undef PREF
#undef GADDR

  float4 o = {s[0], s[1], s[2], s[3]};
  *(float4*)(Sout + ((size_t)b * NST + r) * NST + j0) = o;
}

extern "C" void kernel_launch(void* const* d_in, const int* in_sizes, int n_in,
                              void* d_out, int out_size, void* d_ws, size_t ws_size,
                              hipStream_t stream) {
  const float* x  = (const float*)d_in[0];
  const float* S0 = (const float*)d_in[1];
  const float* Wk = (const float*)d_in[2];
  const float* Wv = (const float*)d_in[3];
  const float* Wq = (const float*)d_in[4];
  const float* Wa = (const float*)d_in[5];
  const float* da = (const float*)d_in[6];
  const float* ba = (const float*)d_in[7];

  float* out  = (float*)d_out;                        // [T,B,64]
  float* Sout = out + (size_t)T_STEPS * BATCH * NST;  // [B,64,64]
  _Float16* projh = (_Float16*)d_ws;                  // [16384][256] fp16 = 8 MB
  _Float16* Wc = (_Float16*)((char*)d_ws + (size_t)16384 * 256 * 2);  // 512 KB

  wconv<<<256, 256, 0, stream>>>(Wk, Wv, Wq, Wa, Wc);
  proj_gemm<<<256, 512, 0, stream>>>(x, Wc, projh);
  scan_kernel<<<4 * BATCH, 256, 0, stream>>>(projh, S0, da, ba, out, Sout);
}

// Round 4
// 218.182 us; speedup vs baseline: 1.0673x; 1.0309x over previous
//
#include <hip/hip_runtime.h>
#include <hip/hip_bf16.h>

#define T_STEPS 512
#define BATCH 32
#define NST 64
#define DIM 1024

typedef _Float16 f16x8 __attribute__((ext_vector_type(8)));
typedef _Float16 f16x4 __attribute__((ext_vector_type(4)));
typedef float f32x4 __attribute__((ext_vector_type(4)));
typedef float f32x2 __attribute__((ext_vector_type(2)));

__device__ __forceinline__ void gl_lds16(const void* g, void* l) {
  __builtin_amdgcn_global_load_lds(
      (const __attribute__((address_space(1))) void*)g,
      (__attribute__((address_space(3))) void*)l, 16, 0, 0);
}

// ---------------- W concat + fp16 convert ----------------
// Wc[256][1024] fp16, row order [Wk | Wq | Wv | Wa]. Wa pre-scaled by -log2(e)
// so the scan's sigmoid can use exp2 directly.
__global__ __launch_bounds__(256) void wconv(
    const float* __restrict__ Wk, const float* __restrict__ Wv,
    const float* __restrict__ Wq, const float* __restrict__ Wa,
    _Float16* __restrict__ Wc) {
  const int n = blockIdx.x;
  const int g = n >> 6, r = n & 63;
  const float* W = (g == 0) ? Wk : (g == 1) ? Wq : (g == 2) ? Wv : Wa;
  const float sc = (g == 3) ? -1.44269504088896340736f : 1.0f;
  float4 v = *(const float4*)(W + (size_t)r * DIM + threadIdx.x * 4);
  f16x4 h = {(_Float16)(v.x * sc), (_Float16)(v.y * sc), (_Float16)(v.z * sc),
             (_Float16)(v.w * sc)};
  *(f16x4*)(Wc + (size_t)n * DIM + threadIdx.x * 4) = h;
}

// ---------------- Projection GEMM v2 (fp32 output) ----------------
// BM=64, BN=256 (full width -> x read ONCE), BK=32.
// 256 blocks (1/CU), 512 threads = 8 waves (2/SIMD), wave grid 2m x 4n,
// wave tile 32m x 64n. A and B double-buffered in LDS, ONE barrier/K-step.
// projf[m][256] fp32, cols [k(64) | q(64) | v,ax interleaved(128)].
__global__ __launch_bounds__(512) void proj_gemm(
    const float* __restrict__ x, const _Float16* __restrict__ Wc,
    float* __restrict__ projf) {
  const int m0 = blockIdx.x * 64;
  const int tid = threadIdx.x;
  const int lane = tid & 63, wv = tid >> 6;
  const int wm = wv >> 2, wn = wv & 3;
  const int fm = lane & 15, fq = lane >> 4;

  __shared__ __align__(16) _Float16 Bl[2][256 * 32];  // 2 x 16 KB
  __shared__ __align__(16) _Float16 Al[2][64 * 32];   // 2 x 4 KB

  const int brow = tid >> 2;
  const int bcg = (tid & 3) ^ ((tid >> 3) & 3);
  const _Float16* gB = Wc + (size_t)brow * DIM + bcg * 8;
  const int bdst = tid * 8;

#define STAGE_B(buf, k0)                                          \
  {                                                               \
    _Pragma("unroll") for (int i = 0; i < 2; ++i)                 \
        gl_lds16(gB + (size_t)i * 128 * DIM + (k0),               \
                 &Bl[buf][i * 4096 + bdst]);                      \
  }

  const int arow = tid >> 3;
  const int afc = (tid & 7) * 4;
  const float* gA = x + (size_t)(m0 + arow) * DIM + afc;
  const int awp = arow * 32 + ((((tid >> 1) & 3) ^ ((arow >> 1) & 3)) * 8) +
                  (tid & 1) * 4;

#define LOADX(rr, k0)                          \
  {                                            \
    rr = *(const float4*)(gA + (k0));          \
  }
#define CVT_WRITE_A(buf, rr)                                        \
  {                                                                 \
    f16x4 h = {(_Float16)rr.x, (_Float16)rr.y, (_Float16)rr.z,      \
               (_Float16)rr.w};                                     \
    *(f16x4*)&Al[buf][awp] = h;                                     \
  }

  f32x4 acc[2][4];
#pragma unroll
  for (int mi = 0; mi < 2; ++mi)
#pragma unroll
    for (int ni = 0; ni < 4; ++ni) acc[mi][ni] = (f32x4){0.f, 0.f, 0.f, 0.f};

  const int aswz = (fq ^ ((fm >> 1) & 3)) * 8;
  const int abase = (wm * 32 + fm) * 32 + aswz;
  const int bbase = (wn * 64 + fm) * 32 + aswz;

#define COMPUTE(cb)                                                     \
  {                                                                     \
    f16x8 afr[2], bfr[4];                                               \
    _Pragma("unroll") for (int mi = 0; mi < 2; ++mi)                    \
        afr[mi] = *(const f16x8*)&Al[cb][abase + mi * 16 * 32];         \
    _Pragma("unroll") for (int ni = 0; ni < 4; ++ni)                    \
        bfr[ni] = *(const f16x8*)&Bl[cb][bbase + ni * 16 * 32];         \
    _Pragma("unroll") for (int mi = 0; mi < 2; ++mi)                    \
        _Pragma("unroll") for (int ni = 0; ni < 4; ++ni)                \
            acc[mi][ni] = __builtin_amdgcn_mfma_f32_16x16x32_f16(       \
                afr[mi], bfr[ni], acc[mi][ni], 0, 0, 0);                \
  }

  float4 rE, rO;
  LOADX(rE, 0);
  STAGE_B(0, 0);
  LOADX(rO, 32);
  CVT_WRITE_A(0, rE);
  __syncthreads();

  for (int k2 = 0; k2 < 16; ++k2) {
    STAGE_B(1, (2 * k2 + 1) * 32);
    if (k2 < 15) LOADX(rE, (2 * k2 + 2) * 32);
    CVT_WRITE_A(1, rO);
    COMPUTE(0);
    __syncthreads();
    if (k2 < 15) {
      STAGE_B(0, (2 * k2 + 2) * 32);
      LOADX(rO, (2 * k2 + 3) * 32);
      CVT_WRITE_A(0, rE);
    }
    COMPUTE(1);
    __syncthreads();
  }
#undef STAGE_B
#undef LOADX
#undef CVT_WRITE_A
#undef COMPUTE

  // C/D: col = lane&15, row = (lane>>4)*4 + reg. Remap cols: v,ax interleaved.
#pragma unroll
  for (int mi = 0; mi < 2; ++mi)
#pragma unroll
    for (int ni = 0; ni < 4; ++ni) {
      const int gcol = wn * 64 + ni * 16 + fm;
      const int pcol = gcol < 128 ? gcol
                     : (gcol < 192 ? 128 + 2 * (gcol - 128) : 129 + 2 * (gcol - 192));
#pragma unroll
      for (int r = 0; r < 4; ++r) {
        const int grow = m0 + wm * 32 + mi * 16 + fq * 4 + r;
        projf[(size_t)grow * 256 + pcol] = acc[mi][ni][r];
      }
    }
}

// ---------------- Sequential scan (fp32 proj, deferred output) ----------------
// 128 blocks = (b, 16-row group rg), 256 threads = 16 rows x 16 lanes.
// Thread (r, c) owns S[b][r][4c..4c+3]. 16-lane allreduce via DPP.
// Per step: NO cvts (fp32 proj), NO global store. Raw h -> hbuf[8][16]
// (OWN 16 rows only!); gated output h^2*sigmoid(h) computed & stored once
// per 8-step chunk into this block's own row slice, coalesced float2.
__device__ __forceinline__ float red16(float x) {
  int v = __builtin_amdgcn_update_dpp(0, __float_as_int(x), 0xB1, 0xF, 0xF, true);
  x += __int_as_float(v);
  v = __builtin_amdgcn_update_dpp(0, __float_as_int(x), 0x4E, 0xF, 0xF, true);
  x += __int_as_float(v);
  v = __builtin_amdgcn_update_dpp(0, __float_as_int(x), 0x124, 0xF, 0xF, true);
  x += __int_as_float(v);
  v = __builtin_amdgcn_update_dpp(0, __float_as_int(x), 0x128, 0xF, 0xF, true);
  x += __int_as_float(v);
  return x;
}

__global__ __launch_bounds__(256, 1) void scan_kernel(
    const float* __restrict__ projf, const float* __restrict__ S0,
    const float* __restrict__ d_alpha, const float* __restrict__ b_alpha,
    float* __restrict__ out, float* __restrict__ Sout) {
  const int b = blockIdx.x >> 2;
  const int rg = blockIdx.x & 3;
  const int tid = threadIdx.x;
  const int c = tid & 15;            // column lane
  const int lr = tid >> 4;           // local row 0..15
  const int r = rg * 16 + lr;
  const int j0 = c * 4;

  __shared__ __align__(16) float lbuf[2 * 2048];  // 2 chunks x 8 steps x 256 f32
  __shared__ __align__(16) float hbuf[8 * 16];    // raw h, own rows only

  constexpr float NL2E = -1.44269504088896340736f;
  f32x2 s01, s23;
  {
    float4 v = *(const float4*)(S0 + ((size_t)b * NST + r) * NST + j0);
    s01 = (f32x2){v.x, v.y}; s23 = (f32x2){v.z, v.w};
  }
  const float da2 = d_alpha[r] * NL2E;
  const float ba2 = b_alpha[r] * NL2E;

  const float* gp = projf + (size_t)b * 256;
  const int lidx = (tid >> 5) * 256 + (tid & 31) * 8;
#define GADDR(ch) (gp + (size_t)((ch) * 8 + (tid >> 5)) * (BATCH * 256) + (tid & 31) * 8)

  float4 rA0, rA1;
  rA0 = *(const float4*)GADDR(0); rA1 = *(const float4*)(GADDR(0) + 4);
  *(float4*)(lbuf + lidx) = rA0; *(float4*)(lbuf + lidx + 4) = rA1;
  rA0 = *(const float4*)GADDR(1); rA1 = *(const float4*)(GADDR(1) + 4);
  *(float4*)(lbuf + 2048 + lidx) = rA0; *(float4*)(lbuf + 2048 + lidx + 4) = rA1;
  rA0 = *(const float4*)GADDR(2); rA1 = *(const float4*)(GADDR(2) + 4);
  __syncthreads();

  f32x2 k01[2], k23[2], q01[2], q23[2], va[2];
#define PREF(tn)                                                            \
  {                                                                         \
    const int pp = (tn) & 1;                                                \
    const float* Pn = lbuf + (((tn) >> 3) & 1) * 2048 + ((tn) & 7) * 256;   \
    float4 kk = *(const float4*)(Pn + j0);                                  \
    float4 qq = *(const float4*)(Pn + 64 + j0);                             \
    k01[pp] = (f32x2){kk.x, kk.y}; k23[pp] = (f32x2){kk.z, kk.w};           \
    q01[pp] = (f32x2){qq.x, qq.y}; q23[pp] = (f32x2){qq.z, qq.w};           \
    float2 vv = *(const float2*)(Pn + 128 + 2 * r);                         \
    va[pp] = (f32x2){vv.x, vv.y};                                           \
  }

  PREF(0);
  for (int ch = 0; ch < 64; ++ch) {
#pragma unroll
    for (int si = 0; si < 8; ++si) {
      const int t = ch * 8 + si;
      const int p = t & 1;
      if (t + 1 < T_STEPS) PREF(t + 1);

      // retrieved = S[r,:] . k  (packed pairs + 16-lane allreduce)
      f32x2 pa = s01 * k01[p] + s23 * k23[p];
      const float rr = red16(pa[0] + pa[1]);

      // z2 = -log2e * (ax + da*rr + ba); alpha = 1/(1+exp2(z2))
      float z2 = fmaf(da2, rr, va[p][1] + ba2);
      z2 = fminf(fmaxf(z2, -43.3f), 43.3f);  // == clamp z to +-30, inf-safe
      const float e = __builtin_amdgcn_exp2f(z2);          // exp(-z)
      const float al = __builtin_amdgcn_rcpf(1.f + e);     // sigmoid(z)
      const float cc = (e * va[p][0]) * al;                // (1-al)*v

      const f32x2 al2 = {al, al}, cc2 = {cc, cc};
      s01 = al2 * s01 + cc2 * k01[p];
      s23 = al2 * s23 + cc2 * k23[p];

      f32x2 hh = s01 * q01[p] + s23 * q23[p];
      const float h = red16(hh[0] + hh[1]);
      if (c == 0) hbuf[si * 16 + lr] = h;  // raw h; gating deferred to flush
    }
    __syncthreads();  // hbuf complete; lbuf[ch&1] readers done
    if (ch + 2 < 64) {
      *(float4*)(lbuf + (ch & 1) * 2048 + lidx) = rA0;
      *(float4*)(lbuf + (ch & 1) * 2048 + lidx + 4) = rA1;
    }
    if (tid < 64) {  // flush own 16-row slice: y = h*h*sigmoid(h)
      const int tl = tid >> 3;        // step within chunk
      const int pr = (tid & 7) * 2;   // local row pair
      float2 hv = *(const float2*)(hbuf + tl * 16 + pr);
      const float e0 = __builtin_amdgcn_exp2f(hv.x * NL2E);
      const float e1 = __builtin_amdgcn_exp2f(hv.y * NL2E);
      float2 y;
      y.x = (hv.x * hv.x) * __builtin_amdgcn_rcpf(1.f + e0);
      y.y = (hv.y * hv.y) * __builtin_amdgcn_rcpf(1.f + e1);
      *(float2*)(out + ((size_t)(ch * 8 + tl) * BATCH + b) * NST + rg * 16 + pr) = y;
    }
    if (ch + 3 < 64) {
      rA0 = *(const float4*)GADDR(ch + 3);
      rA1 = *(const float4*)(GADDR(ch + 3) + 4);
    }
    __syncthreads();  // lbuf/hbuf safe for next chunk
  }
#undef PREF
#undef GADDR

  float4 o = {s01[0], s01[1], s23[0], s23[1]};
  *(float4*)(Sout + ((size_t)b * NST + r) * NST + j0) = o;
}

extern "C" void kernel_launch(void* const* d_in, const int* in_sizes, int n_in,
                              void* d_out, int out_size, void* d_ws, size_t ws_size,
                              hipStream_t stream) {
  const float* x  = (const float*)d_in[0];
  const float* S0 = (const float*)d_in[1];
  const float* Wk = (const float*)d_in[2];
  const float* Wv = (const float*)d_in[3];
  const float* Wq = (const float*)d_in[4];
  const float* Wa = (const float*)d_in[5];
  const float* da = (const float*)d_in[6];
  const float* ba = (const float*)d_in[7];

  float* out  = (float*)d_out;                        // [T,B,64]
  float* Sout = out + (size_t)T_STEPS * BATCH * NST;  // [B,64,64]
  float* projf = (float*)d_ws;                        // [16384][256] f32 = 16 MB
  _Float16* Wc = (_Float16*)((char*)d_ws + (size_t)16384 * 256 * 4);  // 512 KB

  wconv<<<256, 256, 0, stream>>>(Wk, Wv, Wq, Wa, Wc);
  proj_gemm<<<256, 512, 0, stream>>>(x, Wc, projf);
  scan_kernel<<<4 * BATCH, 256, 0, stream>>>(projf, S0, da, ba, out, Sout);
}

// Round 5
// 210.571 us; speedup vs baseline: 1.1059x; 1.0361x over previous
//
#include <hip/hip_runtime.h>
#include <hip/hip_bf16.h>

#define T_STEPS 512
#define BATCH 32
#define NST 64
#define DIM 1024

typedef _Float16 f16x8 __attribute__((ext_vector_type(8)));
typedef _Float16 f16x4 __attribute__((ext_vector_type(4)));
typedef float f32x4 __attribute__((ext_vector_type(4)));
typedef float f32x2 __attribute__((ext_vector_type(2)));

__device__ __forceinline__ void gl_lds16(const void* g, void* l) {
  __builtin_amdgcn_global_load_lds(
      (const __attribute__((address_space(1))) void*)g,
      (__attribute__((address_space(3))) void*)l, 16, 0, 0);
}

// ---------------- W concat + fp16 convert ----------------
// Wc[256][1024] fp16, row order [Wk | Wq | Wv | Wa]. Wa pre-scaled by -log2(e)
// so the scan's sigmoid can use exp2 directly.
__global__ __launch_bounds__(256) void wconv(
    const float* __restrict__ Wk, const float* __restrict__ Wv,
    const float* __restrict__ Wq, const float* __restrict__ Wa,
    _Float16* __restrict__ Wc) {
  const int n = blockIdx.x;
  const int g = n >> 6, r = n & 63;
  const float* W = (g == 0) ? Wk : (g == 1) ? Wq : (g == 2) ? Wv : Wa;
  const float sc = (g == 3) ? -1.44269504088896340736f : 1.0f;
  float4 v = *(const float4*)(W + (size_t)r * DIM + threadIdx.x * 4);
  f16x4 h = {(_Float16)(v.x * sc), (_Float16)(v.y * sc), (_Float16)(v.z * sc),
             (_Float16)(v.w * sc)};
  *(f16x4*)(Wc + (size_t)n * DIM + threadIdx.x * 4) = h;
}

// ---------------- Projection GEMM v2 (fp32 output) ----------------
// BM=64, BN=256 (full width -> x read ONCE), BK=32.
// 256 blocks (1/CU), 512 threads = 8 waves (2/SIMD), wave grid 2m x 4n,
// wave tile 32m x 64n. A and B double-buffered in LDS, ONE barrier/K-step.
// projf[m][256] fp32, cols [k(64) | q(64) | v,ax interleaved(128)].
__global__ __launch_bounds__(512) void proj_gemm(
    const float* __restrict__ x, const _Float16* __restrict__ Wc,
    float* __restrict__ projf) {
  const int m0 = blockIdx.x * 64;
  const int tid = threadIdx.x;
  const int lane = tid & 63, wv = tid >> 6;
  const int wm = wv >> 2, wn = wv & 3;
  const int fm = lane & 15, fq = lane >> 4;

  __shared__ __align__(16) _Float16 Bl[2][256 * 32];  // 2 x 16 KB
  __shared__ __align__(16) _Float16 Al[2][64 * 32];   // 2 x 4 KB

  const int brow = tid >> 2;
  const int bcg = (tid & 3) ^ ((tid >> 3) & 3);
  const _Float16* gB = Wc + (size_t)brow * DIM + bcg * 8;
  const int bdst = tid * 8;

#define STAGE_B(buf, k0)                                          \
  {                                                               \
    _Pragma("unroll") for (int i = 0; i < 2; ++i)                 \
        gl_lds16(gB + (size_t)i * 128 * DIM + (k0),               \
                 &Bl[buf][i * 4096 + bdst]);                      \
  }

  const int arow = tid >> 3;
  const int afc = (tid & 7) * 4;
  const float* gA = x + (size_t)(m0 + arow) * DIM + afc;
  const int awp = arow * 32 + ((((tid >> 1) & 3) ^ ((arow >> 1) & 3)) * 8) +
                  (tid & 1) * 4;

#define LOADX(rr, k0)                          \
  {                                            \
    rr = *(const float4*)(gA + (k0));          \
  }
#define CVT_WRITE_A(buf, rr)                                        \
  {                                                                 \
    f16x4 h = {(_Float16)rr.x, (_Float16)rr.y, (_Float16)rr.z,      \
               (_Float16)rr.w};                                     \
    *(f16x4*)&Al[buf][awp] = h;                                     \
  }

  f32x4 acc[2][4];
#pragma unroll
  for (int mi = 0; mi < 2; ++mi)
#pragma unroll
    for (int ni = 0; ni < 4; ++ni) acc[mi][ni] = (f32x4){0.f, 0.f, 0.f, 0.f};

  const int aswz = (fq ^ ((fm >> 1) & 3)) * 8;
  const int abase = (wm * 32 + fm) * 32 + aswz;
  const int bbase = (wn * 64 + fm) * 32 + aswz;

#define COMPUTE(cb)                                                     \
  {                                                                     \
    f16x8 afr[2], bfr[4];                                               \
    _Pragma("unroll") for (int mi = 0; mi < 2; ++mi)                    \
        afr[mi] = *(const f16x8*)&Al[cb][abase + mi * 16 * 32];         \
    _Pragma("unroll") for (int ni = 0; ni < 4; ++ni)                    \
        bfr[ni] = *(const f16x8*)&Bl[cb][bbase + ni * 16 * 32];         \
    _Pragma("unroll") for (int mi = 0; mi < 2; ++mi)                    \
        _Pragma("unroll") for (int ni = 0; ni < 4; ++ni)                \
            acc[mi][ni] = __builtin_amdgcn_mfma_f32_16x16x32_f16(       \
                afr[mi], bfr[ni], acc[mi][ni], 0, 0, 0);                \
  }

  float4 rE, rO;
  LOADX(rE, 0);
  STAGE_B(0, 0);
  LOADX(rO, 32);
  CVT_WRITE_A(0, rE);
  __syncthreads();

  for (int k2 = 0; k2 < 16; ++k2) {
    STAGE_B(1, (2 * k2 + 1) * 32);
    if (k2 < 15) LOADX(rE, (2 * k2 + 2) * 32);
    CVT_WRITE_A(1, rO);
    COMPUTE(0);
    __syncthreads();
    if (k2 < 15) {
      STAGE_B(0, (2 * k2 + 2) * 32);
      LOADX(rO, (2 * k2 + 3) * 32);
      CVT_WRITE_A(0, rE);
    }
    COMPUTE(1);
    __syncthreads();
  }
#undef STAGE_B
#undef LOADX
#undef CVT_WRITE_A
#undef COMPUTE

  // C/D: col = lane&15, row = (lane>>4)*4 + reg. Remap cols: v,ax interleaved.
#pragma unroll
  for (int mi = 0; mi < 2; ++mi)
#pragma unroll
    for (int ni = 0; ni < 4; ++ni) {
      const int gcol = wn * 64 + ni * 16 + fm;
      const int pcol = gcol < 128 ? gcol
                     : (gcol < 192 ? 128 + 2 * (gcol - 128) : 129 + 2 * (gcol - 192));
#pragma unroll
      for (int r = 0; r < 4; ++r) {
        const int grow = m0 + wm * 32 + mi * 16 + fq * 4 + r;
        projf[(size_t)grow * 256 + pcol] = acc[mi][ni][r];
      }
    }
}

// ---------------- Sequential scan: producer/consumer wave split ----------------
// 128 blocks = (b, 16-row group rg), 512 threads = 8 waves on one CU
// (1 producer wave + 1 consumer wave per SIMD).
// Producer (waves 0-3): 16 rows x 16 lanes; runs the serial recurrence only:
//   retrieved = S.k (red16), alpha = sigmoid, S update; writes {al, cc} per
//   (step, row) into a 2 KB LDS ring. Stream has NO h-dot, NO second red16,
//   NO global stores -> shortest possible in-order critical path.
// Consumer (waves 4-7): replays S_t = al*S + cc*k bit-identically one chunk
// behind (6-cyc pk_fma carried chain), computes h = S.q, y = h^2*sigmoid(h),
// stores out + final Sout. All its latency is off the producer's path.
// lbuf is a 4-deep ring of 8-step chunks (consumer lags one chunk).
__device__ __forceinline__ float red16(float x) {
  int v = __builtin_amdgcn_update_dpp(0, __float_as_int(x), 0xB1, 0xF, 0xF, true);
  x += __int_as_float(v);
  v = __builtin_amdgcn_update_dpp(0, __float_as_int(x), 0x4E, 0xF, 0xF, true);
  x += __int_as_float(v);
  v = __builtin_amdgcn_update_dpp(0, __float_as_int(x), 0x124, 0xF, 0xF, true);
  x += __int_as_float(v);
  v = __builtin_amdgcn_update_dpp(0, __float_as_int(x), 0x128, 0xF, 0xF, true);
  x += __int_as_float(v);
  return x;
}

__global__ __launch_bounds__(512, 1) void scan_kernel(
    const float* __restrict__ projf, const float* __restrict__ S0,
    const float* __restrict__ d_alpha, const float* __restrict__ b_alpha,
    float* __restrict__ out, float* __restrict__ Sout) {
  const int b = blockIdx.x >> 2;
  const int rg = blockIdx.x & 3;
  const int tid = threadIdx.x;
  const bool prod = tid < 256;
  const int ptid = tid & 255;
  const int c = ptid & 15;           // column lane
  const int lr = ptid >> 4;          // local row 0..15
  const int r = rg * 16 + lr;
  const int j0 = c * 4;

  __shared__ __align__(16) float lbuf[4][2048];   // 4-ring x (8 steps x 256) f32
  __shared__ __align__(16) float2 alcc[2][8][16]; // {al, cc} handoff, 2 KB

  constexpr float NL2E = -1.44269504088896340736f;
  f32x2 s01, s23;
  {
    float4 v = *(const float4*)(S0 + ((size_t)b * NST + r) * NST + j0);
    s01 = (f32x2){v.x, v.y}; s23 = (f32x2){v.z, v.w};
  }
  const float da2 = d_alpha[r] * NL2E;
  const float ba2 = b_alpha[r] * NL2E;

  // staging: 512 threads x 1 float4 = one 8-step chunk (8 KB)
  const int sstep = tid >> 6;         // 0..7
  const int soff = (tid & 63) * 4;    // 0..252
  const int lidx = sstep * 256 + soff;
  const float* gp = projf + (size_t)b * 256;
#define GADDR(ch) (gp + (size_t)((ch) * 8 + sstep) * (BATCH * 256) + soff)

  float4 rA;
  rA = *(const float4*)GADDR(0); *(float4*)&lbuf[0][lidx] = rA;
  rA = *(const float4*)GADDR(1); *(float4*)&lbuf[1][lidx] = rA;
  rA = *(const float4*)GADDR(2);
  __syncthreads();

  f32x2 k01[2], k23[2], q01[2], q23[2], vaf[2];
#define PREFP(tn)                                                        \
  {                                                                      \
    const int pp = (tn) & 1;                                             \
    const float* Pn = &lbuf[((tn) >> 3) & 3][((tn) & 7) * 256];          \
    float4 kk = *(const float4*)(Pn + j0);                               \
    k01[pp] = (f32x2){kk.x, kk.y}; k23[pp] = (f32x2){kk.z, kk.w};        \
    float2 vv = *(const float2*)(Pn + 128 + 2 * r);                      \
    vaf[pp] = (f32x2){vv.x, vv.y};                                       \
  }
#define PREFC(tn)                                                        \
  {                                                                      \
    const int pp = (tn) & 1;                                             \
    const float* Pn = &lbuf[((tn) >> 3) & 3][((tn) & 7) * 256];          \
    float4 kk = *(const float4*)(Pn + j0);                               \
    k01[pp] = (f32x2){kk.x, kk.y}; k23[pp] = (f32x2){kk.z, kk.w};        \
    float4 qq = *(const float4*)(Pn + 64 + j0);                          \
    q01[pp] = (f32x2){qq.x, qq.y}; q23[pp] = (f32x2){qq.z, qq.w};        \
  }

  if (prod) { PREFP(0); } else { PREFC(0); }

  for (int ch = 0; ch <= 64; ++ch) {
    if (prod) {
      if (ch < 64) {
#pragma unroll
        for (int si = 0; si < 8; ++si) {
          const int t = ch * 8 + si;
          const int p = si & 1;  // == t & 1 (ch*8 even)
          if (t + 1 < T_STEPS) PREFP(t + 1);

          // retrieved = S[r,:].k (packed pairs + 16-lane allreduce)
          f32x2 pa = s01 * k01[p] + s23 * k23[p];
          const float rr = red16(pa[0] + pa[1]);

          float z2 = fmaf(da2, rr, vaf[p][1] + ba2);
          z2 = __builtin_amdgcn_fmed3f(z2, -43.3f, 43.3f);  // clamp, 1 op
          const float e = __builtin_amdgcn_exp2f(z2);          // exp(-z)
          const float al = __builtin_amdgcn_rcpf(1.f + e);     // sigmoid(z)
          const float cc = (e * vaf[p][0]) * al;               // (1-al)*v

          const f32x2 al2 = {al, al}, cc2 = {cc, cc};
          s01 = al2 * s01 + cc2 * k01[p];
          s23 = al2 * s23 + cc2 * k23[p];

          if (c == 0) alcc[ch & 1][si][lr] = make_float2(al, cc);
        }
      }
    } else {
      if (ch >= 1) {
        const int pch = ch - 1;
#pragma unroll
        for (int si = 0; si < 8; ++si) {
          const int t = pch * 8 + si;
          const int p = si & 1;  // == t & 1 (pch*8 even)
          if (t + 1 < T_STEPS) PREFC(t + 1);

          float2 ac = alcc[pch & 1][si][lr];  // broadcast read
          const f32x2 al2 = {ac.x, ac.x}, cc2 = {ac.y, ac.y};
          s01 = al2 * s01 + cc2 * k01[p];  // bit-identical S replay
          s23 = al2 * s23 + cc2 * k23[p];

          f32x2 hh = s01 * q01[p] + s23 * q23[p];
          const float h = red16(hh[0] + hh[1]);
          if (c == 0) {
            const float sg =
                __builtin_amdgcn_rcpf(1.f + __builtin_amdgcn_exp2f(h * NL2E));
            out[((size_t)t * BATCH + b) * NST + r] = (h * h) * sg;
          }
        }
      }
    }
    __syncthreads();  // alcc handoff; lbuf readers of retiring buffer done
    if (ch + 2 < 64) *(float4*)&lbuf[(ch + 2) & 3][lidx] = rA;
    if (ch + 3 < 64) rA = *(const float4*)GADDR(ch + 3);
    __syncthreads();  // staged chunk visible
  }
#undef PREFP
#undef PREFC
#undef GADDR

  if (!prod) {
    float4 o = {s01[0], s01[1], s23[0], s23[1]};
    *(float4*)(Sout + ((size_t)b * NST + r) * NST + j0) = o;
  }
}

extern "C" void kernel_launch(void* const* d_in, const int* in_sizes, int n_in,
                              void* d_out, int out_size, void* d_ws, size_t ws_size,
                              hipStream_t stream) {
  const float* x  = (const float*)d_in[0];
  const float* S0 = (const float*)d_in[1];
  const float* Wk = (const float*)d_in[2];
  const float* Wv = (const float*)d_in[3];
  const float* Wq = (const float*)d_in[4];
  const float* Wa = (const float*)d_in[5];
  const float* da = (const float*)d_in[6];
  const float* ba = (const float*)d_in[7];

  float* out  = (float*)d_out;                        // [T,B,64]
  float* Sout = out + (size_t)T_STEPS * BATCH * NST;  // [B,64,64]
  float* projf = (float*)d_ws;                        // [16384][256] f32 = 16 MB
  _Float16* Wc = (_Float16*)((char*)d_ws + (size_t)16384 * 256 * 4);  // 512 KB

  wconv<<<256, 256, 0, stream>>>(Wk, Wv, Wq, Wa, Wc);
  proj_gemm<<<256, 512, 0, stream>>>(x, Wc, projf);
  scan_kernel<<<4 * BATCH, 512, 0, stream>>>(projf, S0, da, ba, out, Sout);
}